// Round 11
// baseline (297.310 us; speedup 1.0000x reference)
//
#include <hip/hip_runtime.h>
#include <cstdint>
#include <climits>
#include <cstddef>

#define TK 13
#define MAXG 128
#define CAP 192
#define NW 8
#define MCAP 24576

__device__ __forceinline__ float iou_fn(const float4 pb, const float4 gb){
  float pa = (pb.z - pb.x) * (pb.w - pb.y);
  float ga = (gb.z - gb.x) * (gb.w - gb.y);
  float ltx = fmaxf(pb.x, gb.x), lty = fmaxf(pb.y, gb.y);
  float rbx = fminf(pb.z, gb.z), rby = fminf(pb.w, gb.w);
  float w = fmaxf(rbx - ltx, 0.0f), h = fmaxf(rby - lty, 0.0f);
  float inter = w * h;
  float uni = pa + ga - inter;
  return inter / fmaxf(uni, 1e-6f);
}

__device__ __forceinline__ float sigmoid_f(float x){ return 1.0f / (1.0f + expf(-x)); }

// Same expression order as R0-R10 (passed absmax 0) — do not alter.
__device__ __forceinline__ float cost_full(float iou, float s, float dist){
  float sig = sigmoid_f(s);
  float iouc = -logf(iou + 1e-7f) * 3.0f;
  float scale = iou - sig;
  float bce = fmaxf(s, 0.0f) + log1pf(expf(-fabsf(s))) - s * iou;
  float cls = bce * scale * scale;
  float soft = powf(10.0f, dist - 3.0f);
  return cls + iouc + soft;
}

__device__ __forceinline__ void bfly_max_u64(unsigned long long &v, int &l){
  #pragma unroll
  for (int off = 32; off >= 1; off >>= 1){
    unsigned long long ov = __shfl_xor(v, off);
    int ol = __shfl_xor(l, off);
    if (ov > v){ v = ov; l = ol; }
  }
}

// wave-level: find 13th-largest of cnt entries in buf; compact top-13 to
// buf[0..12]; return 13th key (0 if fewer than 13 nonzero). Keys unique.
__device__ __forceinline__ unsigned long long squeeze13(unsigned long long* buf, int& cnt, int lane){
  unsigned long long e0 = (lane < cnt) ? buf[lane] : 0ull;
  unsigned long long e1 = (lane + 64 < cnt) ? buf[lane + 64] : 0ull;
  unsigned long long e2 = (lane + 128 < cnt) ? buf[lane + 128] : 0ull;
  if (e0 < e2){ unsigned long long t = e0; e0 = e2; e2 = t; }
  if (e0 < e1){ unsigned long long t = e0; e0 = e1; e1 = t; }
  if (e1 < e2){ unsigned long long t = e1; e1 = e2; e2 = t; }
  unsigned long long T = 0;
  for (int r = 0; r < TK; ++r){
    unsigned long long m = e0; int l = lane;
    bfly_max_u64(m, l);
    if (lane == 0) buf[r] = m;
    T = m;
    if (lane == l){ e0 = e1; e1 = e2; e2 = 0ull; }
  }
  cnt = TK;
  return T;
}

// Kernel A: valid bitmask + acc init + multi-counter zero.
__global__ __launch_bounds__(256) void k_valid(
    const float4* __restrict__ priors, const float4* __restrict__ gtb,
    const float* __restrict__ pad, unsigned long long* __restrict__ vmask,
    unsigned int* __restrict__ acc, unsigned int* __restrict__ mcnt,
    int P, int G, int nCh)
{
  int b = blockIdx.y;
  int p = blockIdx.x * 256 + threadIdx.x;
  if (b == 0 && p == 0) *mcnt = 0u;
  __shared__ float4 sg[MAXG];
  __shared__ float sp[MAXG];
  for (int i = threadIdx.x; i < G; i += 256){ sg[i] = gtb[b*G + i]; sp[i] = pad[b*G + i]; }
  __syncthreads();
  if (p >= P) return;
  float4 pr = priors[p];
  bool v = false;
  #pragma unroll 4
  for (int g = 0; g < G; ++g){
    float4 gb = sg[g];
    bool ig = (pr.x > gb.x) && (pr.y > gb.y) && (gb.z > pr.x) && (gb.w > pr.y);
    v = v || (ig && sp[g] > 0.5f);
  }
  size_t o = (size_t)b * P + p;
  acc[o] = 0u;
  unsigned long long m = __ballot(v);
  if ((threadIdx.x & 63) == 0) vmask[(size_t)b * nCh + (p >> 6)] = m;
}

// Kernel B: one 8-wave block per (b,g). Flood-free scan (fill pools for
// zero-metric / invalid-cost keys); per-wave candidate buffers + register
// thresholds; shared LDS bounds updated only at squeezes; wave0 extracts
// global top-13 from 8x13 survivors (2 entries/lane) and scatters.
__global__ __launch_bounds__(512) void k_scan(
    const float4* __restrict__ pred_bboxes, const float* __restrict__ pred_scores,
    const float4* __restrict__ priors, const int* __restrict__ gt_labels,
    const float4* __restrict__ gtbb, const float* __restrict__ pad,
    const unsigned long long* __restrict__ vmask,
    unsigned int* __restrict__ acc, unsigned int* __restrict__ mcnt,
    unsigned int* __restrict__ mlist,
    int P, int G, int C, int nCh)
{
  int bg = blockIdx.x;
  if (pad[bg] <= 0.5f) return;
  int b = bg / G;
  int g = bg - b * G;
  int tid = threadIdx.x;
  int lane = tid & 63;
  int wv = tid >> 6;
  float4 gb = gtbb[bg];
  int lbl = gt_labels[bg];
  float gcx = (gb.x + gb.z) * 0.5f, gcy = (gb.y + gb.w) * 0.5f;
  size_t bP = (size_t)b * P;
  const unsigned long long* vmb = vmask + (size_t)b * nCh;

  __shared__ unsigned long long bufM[NW*CAP], bufC[NW*CAP], bufI[NW*CAP];
  __shared__ unsigned int shwC, shwM, shwI;   // value-bits-only shared bounds
  if (tid == 0){ shwC = 0xFFFFFFFFu; shwM = 0u; shwI = 0u; }
  __syncthreads();
  unsigned long long* bM = bufM + wv*CAP;
  unsigned long long* bC = bufC + wv*CAP;
  unsigned long long* bI = bufI + wv*CAP;

  int cntM = 0, cntC = 0, cntI = 0;                 // wave-uniform
  int zM = 0, zC = 0;                               // fill-pool counts (wave-uniform)
  unsigned long long Tm = 0ull, Tc = 0ull;
  unsigned long long Ti = 0x00000000FFFFFFFFull;    // prune iou==0 from the start
  unsigned cbits = 0xFFFFFFFFu, mBbits = 0u, iBb = 0u;
  float thr = 1e30f, mB = 0.0f;
  unsigned long long laneLT = (1ull << lane) - 1ull;

  int p = wv * 64 + lane;
  bool inb = p < P;
  float4 pr = make_float4(0,0,0,0), pb = pr; bool vb = false;
  if (inb){
    pr = priors[p]; pb = pred_bboxes[bP + p]; vb = (vmb[wv] >> lane) & 1ull;
  }
  for (int c = wv; c < nCh; c += NW){
    // prefetch next chunk for this wave
    int cn = c + NW;
    int pn = cn * 64 + lane;
    bool inbn = (cn < nCh) && (pn < P);
    float4 prn = make_float4(0,0,0,0), pbn = prn; bool vbn = false;
    if (inbn){
      prn = priors[pn]; pbn = pred_bboxes[bP + pn]; vbn = (vmb[cn] >> (pn & 63)) & 1ull;
    }
    // refresh shared bounds (broadcast LDS reads; recompute thr only on change)
    { unsigned sC = shwC; if (sC < cbits){ cbits = sC;
        thr = 3.0f + log10f(__uint_as_float(cbits) * 1.00002f + 1e-6f); } }
    { unsigned sM = shwM; if (sM > mBbits){ mBbits = sM; mB = __uint_as_float(sM); } }
    { unsigned sI = shwI; if (sI > iBb) iBb = sI; }
    // ---- compute ----
    float iou = iou_fn(pb, gb);
    bool ig = inb && (pr.x > gb.x) && (pr.y > gb.y) && (gb.z > pr.x) && (gb.w > pr.y);
    bool pos = ig && (iou > 0.0f);                  // metric > 0 possible only here
    unsigned long long keyI = ((unsigned long long)__float_as_uint(iou) << 32) | (unsigned)p;
    bool candI = inb && (keyI > Ti) && !((unsigned)(keyI >> 32) < iBb);
    float i2 = iou * iou;
    float bnd = (i2 * i2) * i2 * 1.000002f;         // >= sigmoid*powf(iou,6)
    bool needm = pos && !(bnd < mB);
    float dist = 0.0f; bool needc = false;
    if (vb){
      float dx = pr.x - gcx, dy = pr.y - gcy;
      dist = sqrtf(dx*dx + dy*dy) / pr.z;
      needc = !(dist > thr);
    }
    float sc = 0.0f;
    if (needm || needc) sc = pred_scores[(bP + p) * C + lbl];
    unsigned long long keyM = 0;
    if (__ballot(needm)){
      float met = sigmoid_f(sc) * powf(iou, 6.0f);
      if (needm)
        keyM = ((unsigned long long)__float_as_uint(met) << 32)
             | (unsigned)~(unsigned)((p << 1) | 1);
    }
    if (zM < TK && inb && !pos)                     // zero-metric fill pool (13-smallest-p/wave)
      keyM = (unsigned long long)(unsigned)~(unsigned)((p << 1) | (ig ? 1 : 0));
    bool candM = (keyM != 0ull) && (keyM > Tm) && !((unsigned)(keyM >> 32) < mBbits);
    unsigned long long keyC = 0;
    if (zC < TK && inb && !vb)                      // invalid-cost fill pool
      keyC = ~(((unsigned long long)__float_as_uint(1e8f) << 32) | (unsigned)p);
    if (__ballot(needc)){
      float cst = cost_full(iou, sc, dist);
      if (needc)
        keyC = ~(((unsigned long long)__float_as_uint(cst) << 32) | (unsigned)p);
    }
    bool candC = (keyC != 0ull) && (keyC > Tc) && !((unsigned)((~keyC) >> 32) > cbits);
    // ---- pushes (squeeze-on-full; shared bound update at squeeze only) ----
    if (cntI > CAP - 64){
      Ti = squeeze13(bI, cntI, lane);
      unsigned ib = (unsigned)(Ti >> 32);
      if (ib > iBb) iBb = ib;
      if (lane == 0 && ib) atomicMax(&shwI, ib);
      candI = candI && (keyI > Ti) && !((unsigned)(keyI >> 32) < iBb);
    }
    { unsigned long long mk = __ballot(candI);
      if (mk){ int off = cntI + __popcll(mk & laneLT); if (candI) bI[off] = keyI; cntI += __popcll(mk); } }
    if (cntM > CAP - 64){
      Tm = squeeze13(bM, cntM, lane);
      unsigned tb = (unsigned)(Tm >> 32);
      if (tb > mBbits){ mBbits = tb; mB = __uint_as_float(tb); }
      if (lane == 0 && tb) atomicMax(&shwM, tb);
      candM = candM && (keyM > Tm) && !((unsigned)(keyM >> 32) < mBbits);
    }
    { unsigned long long mk = __ballot(candM);
      if (mk){
        int off = cntM + __popcll(mk & laneLT);
        if (candM) bM[off] = keyM;
        cntM += __popcll(mk);
        unsigned long long zk = __ballot(candM && !pos);
        zM += __popcll(zk);
      } }
    if (cntC > CAP - 64){
      Tc = squeeze13(bC, cntC, lane);
      unsigned cb = (unsigned)((~Tc) >> 32);
      if (cb < cbits){ cbits = cb;
        thr = 3.0f + log10f(__uint_as_float(cbits) * 1.00002f + 1e-6f); }
      if (lane == 0) atomicMin(&shwC, cb);
      candC = candC && (keyC > Tc) && !((unsigned)((~keyC) >> 32) > cbits);
    }
    { unsigned long long mk = __ballot(candC);
      if (mk){
        int off = cntC + __popcll(mk & laneLT);
        if (candC) bC[off] = keyC;
        cntC += __popcll(mk);
        unsigned long long zk = __ballot(candC && !vb);
        zC += __popcll(zk);
      } }

    p = pn; inb = inbn; pr = prn; pb = pbn; vb = vbn;
  }

  // per-wave: compact own buffers to exact top-13 at buf[0..12]
  squeeze13(bI, cntI, lane);
  squeeze13(bM, cntM, lane);
  squeeze13(bC, cntC, lane);
  __syncthreads();
  if (wv != 0) return;

  // ---- wave0: global top-13 from 8x13 survivors per criterion (2/lane) ----
  int i0 = lane, i1 = lane + 64;
  int w0 = i0 / TK, r0 = i0 - w0 * TK;
  int w1 = i1 / TK, r1 = i1 - w1 * TK;
  int kd;
  { // iou -> dynamic_k (desc-order sum, fp-exact vs ref; zeros land last)
    unsigned long long e0 = (i0 < NW*TK) ? bufI[w0*CAP + r0] : 0ull;
    unsigned long long e1 = (i1 < NW*TK) ? bufI[w1*CAP + r1] : 0ull;
    float ksum = 0.0f;
    for (int r = 0; r < TK; ++r){
      unsigned long long m = e0 > e1 ? e0 : e1; int l = lane;
      bfly_max_u64(m, l);
      ksum += __uint_as_float((unsigned)(m >> 32));
      if (lane == l){ if (e0 == m) e0 = 0ull; else e1 = 0ull; }
    }
    kd = (int)ksum; if (kd < 1) kd = 1;
  }
  { // metric -> fg marks
    unsigned long long e0 = (i0 < NW*TK) ? bufM[w0*CAP + r0] : 0ull;
    unsigned long long e1 = (i1 < NW*TK) ? bufM[w1*CAP + r1] : 0ull;
    for (int r = 0; r < TK; ++r){
      unsigned long long m = e0 > e1 ? e0 : e1; int l = lane;
      bfly_max_u64(m, l);
      if (m == 0ull) break;
      if (lane == 0){
        unsigned ix = ~(unsigned)(m & 0xFFFFFFFFull);
        if (ix & 1u) atomicOr(&acc[bP + (ix >> 1)], 2u);
      }
      if (lane == l){ if (e0 == m) e0 = 0ull; else e1 = 0ull; }
    }
  }
  { // cost -> first kd selections; multi-detect on 1->2 transition
    unsigned long long e0 = (i0 < NW*TK) ? bufC[w0*CAP + r0] : 0ull;
    unsigned long long e1 = (i1 < NW*TK) ? bufC[w1*CAP + r1] : 0ull;
    for (int r = 0; r < kd; ++r){
      unsigned long long m = e0 > e1 ? e0 : e1; int l = lane;
      bfly_max_u64(m, l);
      if (m == 0ull) break;
      if (lane == 0){
        unsigned pp = (unsigned)((~m) & 0xFFFFFFFFull);
        unsigned old = atomicAdd(&acc[bP + pp], (1u << 17) | ((unsigned)g << 2));
        if ((old >> 17) == 1u){
          unsigned mi = atomicAdd(mcnt, 1u);
          if (mi < MCAP) mlist[mi] = (unsigned)(bP + pp);
        }
      }
      if (lane == l){ if (e0 == m) e0 = 0ull; else e1 = 0ull; }
    }
  }
}

// Kernel C: uniform decode; multi priors get a placeholder (k_multi overwrites).
__global__ __launch_bounds__(256) void k_final(
    const float4* __restrict__ pred_bboxes, const int* __restrict__ gt_labels,
    const float4* __restrict__ gtb, const unsigned int* __restrict__ acc,
    float* __restrict__ out, int B, int P, int G)
{
  int b = blockIdx.y;
  int p = blockIdx.x * 256 + threadIdx.x;
  __shared__ float4 sg[MAXG];
  __shared__ int sl[MAXG];
  for (int i = threadIdx.x; i < G; i += 256){
    sg[i] = gtb[b*G + i]; sl[i] = gt_labels[b*G + i];
  }
  __syncthreads();
  if (p >= P) return;
  size_t o = (size_t)b * P + p;
  unsigned int w = acc[o];
  int cnt = (int)(w >> 17);
  bool fg = cnt > 0;
  int mg = (cnt == 1) ? (int)((w >> 2) & 0x7FFFu) : 0;  // cnt>1 -> placeholder
  float4 pb = pred_bboxes[o];
  size_t BP = (size_t)B * P;
  out[o] = fg ? (float)sl[mg] : 80.0f;
  out[BP + o] = 1.0f;
  float4 ob = fg ? sg[mg] : make_float4(0.f, 0.f, 0.f, 0.f);
  ((float4*)(out + 2*BP))[o] = ob;
  out[6*BP + o] = fg ? iou_fn(pb, sg[mg]) : 0.0f;
  out[7*BP + o] = ((w >> 1) & 1u) ? 1.0f : 0.0f;
}

// Kernel D: one wave per multi-matched prior; exact argmin cost over all g.
__global__ __launch_bounds__(256) void k_multi(
    const float4* __restrict__ pred_bboxes, const float* __restrict__ pred_scores,
    const float4* __restrict__ priors, const int* __restrict__ gt_labels,
    const float4* __restrict__ gtb, const unsigned long long* __restrict__ vmask,
    const unsigned int* __restrict__ mcnt, const unsigned int* __restrict__ mlist,
    float* __restrict__ out, int B, int P, int G, int C, int nCh)
{
  unsigned n = *mcnt; if (n > MCAP) n = MCAP;
  int lane = threadIdx.x & 63;
  int wid = (blockIdx.x * (blockDim.x >> 6)) + (threadIdx.x >> 6);
  int nw = gridDim.x * (blockDim.x >> 6);
  size_t BP = (size_t)B * P;
  for (unsigned i = wid; i < n; i += nw){
    unsigned o = mlist[i];
    int b = o / P;
    int p = o - b * P;
    float4 pb = pred_bboxes[o];
    bool vld = (vmask[(size_t)b * nCh + (p >> 6)] >> (p & 63)) & 1ull;
    int mg = 0;
    if (vld){
      float4 pr = priors[p];
      const float* srow = pred_scores + (size_t)o * C;
      unsigned long long best = 0xFFFFFFFFFFFFFFFFull;
      for (int g0 = lane; g0 < G; g0 += 64){
        float4 gbx = gtb[b*G + g0];
        float iou = iou_fn(pb, gbx);
        float s = srow[gt_labels[b*G + g0]];
        float gcx = (gbx.x + gbx.z) * 0.5f, gcy = (gbx.y + gbx.w) * 0.5f;
        float dx = pr.x - gcx, dy = pr.y - gcy;
        float dist = sqrtf(dx*dx + dy*dy) / pr.z;
        float cc = cost_full(iou, s, dist);
        unsigned long long k = ((unsigned long long)__float_as_uint(cc) << 32) | (unsigned)g0;
        if (k < best) best = k;
      }
      #pragma unroll
      for (int off = 32; off >= 1; off >>= 1){
        unsigned long long ov = __shfl_xor(best, off);
        if (ov < best) best = ov;
      }
      mg = (int)(best & 0xFFFFFFFFull);
    }
    if (lane == 0){
      float4 gbx = gtb[b*G + mg];
      out[o] = (float)gt_labels[b*G + mg];
      ((float4*)(out + 2*BP))[o] = gbx;
      out[6*BP + o] = iou_fn(pb, gbx);
    }
  }
}

extern "C" void kernel_launch(void* const* d_in, const int* in_sizes, int n_in,
                              void* d_out, int out_size, void* d_ws, size_t ws_size,
                              hipStream_t stream)
{
  const float4* pred_bboxes = (const float4*)d_in[0];
  const float*  pred_scores = (const float*)d_in[1];
  const float4* priors      = (const float4*)d_in[2];
  const int*    gt_labels   = (const int*)d_in[3];
  const float4* gt_bboxes   = (const float4*)d_in[4];
  const float*  pad         = (const float*)d_in[5];
  int P = in_sizes[2] / 4;                 // 8400
  int B = in_sizes[0] / (P * 4);           // 16
  int C = in_sizes[1] / (B * P);           // 80
  int G = in_sizes[4] / (B * 4);           // 100
  int BG = B * G;
  int nCh = (P + 63) >> 6;                 // 132

  uint8_t* ws = (uint8_t*)d_ws;
  size_t accOff  = (size_t)B * nCh * 8;                 // vmask
  size_t mcntOff = accOff + (size_t)B * P * 4;          // acc
  mcntOff = (mcntOff + 15) & ~(size_t)15;
  size_t mlistOff = mcntOff + 16;

  unsigned long long* vmask = (unsigned long long*)ws;
  unsigned int* acc   = (unsigned int*)(ws + accOff);
  unsigned int* mcnt  = (unsigned int*)(ws + mcntOff);
  unsigned int* mlist = (unsigned int*)(ws + mlistOff);
  float* out = (float*)d_out;

  dim3 gridA((P + 255) / 256, B);
  k_valid<<<gridA, 256, 0, stream>>>(priors, gt_bboxes, pad, vmask, acc, mcnt, P, G, nCh);
  k_scan<<<BG, NW*64, 0, stream>>>(pred_bboxes, pred_scores,
                                   priors, gt_labels, gt_bboxes, pad, vmask,
                                   acc, mcnt, mlist, P, G, C, nCh);
  k_final<<<gridA, 256, 0, stream>>>(pred_bboxes, gt_labels, gt_bboxes, acc, out, B, P, G);
  k_multi<<<64, 256, 0, stream>>>(pred_bboxes, pred_scores, priors, gt_labels, gt_bboxes,
                                  vmask, mcnt, mlist, out, B, P, G, C, nCh);
}